// Round 9
// baseline (236.521 us; speedup 1.0000x reference)
//
#include <hip/hip_runtime.h>
#include <math.h>

#define EPSF 1e-6f
#define NB    1024
#define ND    512
#define NCAND 40000
#define NPAD  40192          // 157 * 256
#define NCHUNK 157           // NPAD / 256 : one partial per (row, 256-col block)
#define LOG2E 1.44269504088896340736f

typedef __attribute__((ext_vector_type(8))) short          bf16x8;
typedef __attribute__((ext_vector_type(8))) unsigned short ushort8;
typedef __attribute__((ext_vector_type(4))) float          f32x4;

// ---------- helpers ----------
__device__ __forceinline__ unsigned short f2bf(float f) {
  union { float f; unsigned int u; } v; v.f = f;
  unsigned int u = v.u;
  return (unsigned short)((u + 0x7FFFu + ((u >> 16) & 1u)) >> 16);  // RNE
}

__device__ __forceinline__ void gload_lds16(const void* g, void* l) {
  __builtin_amdgcn_global_load_lds(
      (const __attribute__((address_space(1))) void*)g,
      (__attribute__((address_space(3))) void*)l, 16, 0, 0);
}

// ---------- fused prep: one kernel does everything pre-GEMM ----------
__global__ __launch_bounds__(256) void prep_all_kernel(
    const float* __restrict__ q, const float* __restrict__ cand,
    const float* __restrict__ bias, const float* __restrict__ curv,
    const int* __restrict__ target,
    unsigned short* __restrict__ qb, unsigned short* __restrict__ cb,
    float* __restrict__ ysq, float4* __restrict__ rcst,
    float* __restrict__ b2, float* __restrict__ tgtl)
{
  const int blk = blockIdx.x;
  const int tid = threadIdx.x, wid = tid >> 6, lane = tid & 63;

  // ---- candidate rows (all blocks) ----
  {
    const long row = (long)blk * 4 + wid;          // < NPAD by grid size
    float vals[8];
    if (row < NCAND) {
      const float4* s = (const float4*)(cand + row * ND + lane * 8);
      float4 a = s[0], b = s[1];
      vals[0]=a.x; vals[1]=a.y; vals[2]=a.z; vals[3]=a.w;
      vals[4]=b.x; vals[5]=b.y; vals[6]=b.z; vals[7]=b.w;
    } else {
      #pragma unroll
      for (int i = 0; i < 8; ++i) vals[i] = 0.f;
    }
    float ss = 0.f; ushort8 o;
    #pragma unroll
    for (int i = 0; i < 8; ++i) { ss = fmaf(vals[i], vals[i], ss); o[i] = f2bf(vals[i]); }
    *(ushort8*)(cb + row * ND + lane * 8) = o;
    #pragma unroll
    for (int m = 1; m < 64; m <<= 1) ss += __shfl_xor(ss, m, 64);
    if (lane == 0) ysq[row] = ss;
  }

  if (blk >= 256) return;

  // ---- b2 fill (256*256 = 65536 >= NPAD) ----
  {
    const int g = blk * 256 + tid;
    if (g < NPAD) b2[g] = (g < NCAND) ? bias[g] * LOG2E : -INFINITY;
  }

  // ---- query rows ----
  {
    const long row = (long)blk * 4 + wid;          // < 1024
    const float4* s = (const float4*)(q + row * ND + lane * 8);
    float4 a = s[0], b = s[1];
    float vals[8] = {a.x,a.y,a.z,a.w,b.x,b.y,b.z,b.w};
    float ss = 0.f; ushort8 o;
    #pragma unroll
    for (int i = 0; i < 8; ++i) { ss = fmaf(vals[i], vals[i], ss); o[i] = f2bf(vals[i]); }
    *(ushort8*)(qb + row * ND + lane * 8) = o;
    #pragma unroll
    for (int m = 1; m < 64; m <<= 1) ss += __shfl_xor(ss, m, 64);
    if (lane == 0) {
      const float c   = curv[row];
      const float scv = sqrtf(c + EPSF);
      const float inv = 1.f / (scv + EPSF);
      rcst[row] = make_float4(-c, fmaf(-c, ss, 1.f), inv, 2.f * c * c * ss);
    }
  }

  // ---- exact fp32 target logit (wave per row) ----
  {
    const int b = blk * 4 + wid;                   // < 1024
    const int t = target[b];
    const float4* qp = (const float4*)(q + (long)b * ND + lane * 8);
    const float4* cp = (const float4*)(cand + (long)t * ND + lane * 8);
    float4 a0 = qp[0], a1 = qp[1], c0 = cp[0], c1 = cp[1];
    float qa[8] = {a0.x,a0.y,a0.z,a0.w,a1.x,a1.y,a1.z,a1.w};
    float ca[8] = {c0.x,c0.y,c0.z,c0.w,c1.x,c1.y,c1.z,c1.w};
    float xy = 0.f, xs = 0.f, ys = 0.f;
    #pragma unroll
    for (int i = 0; i < 8; ++i) {
      xy = fmaf(qa[i], ca[i], xy);
      xs = fmaf(qa[i], qa[i], xs);
      ys = fmaf(ca[i], ca[i], ys);
    }
    #pragma unroll
    for (int m = 1; m < 64; m <<= 1) {
      xy += __shfl_xor(xy, m, 64);
      xs += __shfl_xor(xs, m, 64);
      ys += __shfl_xor(ys, m, 64);
    }
    if (lane == 0) {
      float c  = curv[b];
      float sc = sqrtf(c + EPSF);
      float A  = 1.f - 2.f * c * xy + c * ys;
      float Bc = 1.f - c * xs;
      float nsq = A * A * xs - 2.f * A * Bc * xy + Bc * Bc * ys;
      float den = 1.f - 2.f * c * xy + c * c * xs * ys;
      float dn  = sqrtf(fmaxf(nsq, 0.f)) / (den + EPSF);
      dn = fminf(fmaxf(dn, EPSF), 1.f / (sc + EPSF) - EPSF);
      float tt  = fminf(sc * dn, 1.f - EPSF);
      float dist = 2.f / (sc + EPSF) * atanhf(tt);
      tgtl[b] = bias[t] - dist;
    }
  }
}

// ---------- fused bf16 GEMM + acosh epilogue + partial expsum ----------
// 256x256 tile, BK=64, 512 threads (8 waves in 2x4), per-wave 128x64 output
// (acc[8][4] frags of 16x16x32). Double-buffered K-tiles, ONE barrier per
// tile: STAGE(next tile -> other buf) issued right after the barrier, so the
// barrier's implicit vmcnt(0) drain has a full tile (~600+ cyc) of lead.
// LDS layout/swizzle identical to the R5-proven zero-conflict BK=64 scheme.
__global__ __launch_bounds__(512, 2) void gemm_epi_kernel(
    const unsigned short* __restrict__ Qb,   // [NB][ND] bf16
    const unsigned short* __restrict__ Cb,   // [NPAD][ND] bf16
    const float4* __restrict__ rcst,         // [NB] (negc, Bc, inv, 2c^2xs)
    const float* __restrict__ ysq,           // [NPAD]
    const float* __restrict__ b2,            // [NPAD] bias*log2e, pad=-inf
    float* __restrict__ partials)            // [NB][NCHUNK]
{
  __shared__ unsigned short As[2][256 * 64];   // 64 KB
  __shared__ unsigned short Bs[2][256 * 64];   // 64 KB

  const int tid  = threadIdx.x;
  const int lane = tid & 63;
  const int wid  = tid >> 6;         // 0..7
  const int wr   = wid >> 2;         // 0..1 (M half)
  const int wc   = wid & 3;          // 0..3 (N quarter)
  const int l15  = lane & 15, l4 = lane >> 4;

  // bijective XCD remap (m204 variant): nwg = 628 = 8*78 + 4
  const int orig = blockIdx.x;
  const int xcd  = orig & 7;
  const int base = (xcd < 4) ? xcd * 79 : 316 + (xcd - 4) * 78;
  const int wg   = base + (orig >> 3);
  const int bm   = wg & 3, bn = wg >> 2;

  f32x4 acc[8][4] = {};

  const unsigned short* qbase = Qb + (long)bm * 256 * ND;
  const unsigned short* cbase = Cb + (long)bn * 256 * ND;

  // staging: e in [0,2048), r = e>>3, physical chunk e&7 holds source chunk
  // (e&7)^(r&7); LDS dest linear (wave-uniform base + lane*16).
  const unsigned short* qsrc[4];
  const unsigned short* csrc[4];
  #pragma unroll
  for (int j = 0; j < 4; ++j) {
    const int e = j * 512 + tid;
    const int r = e >> 3;
    const int s = ((e & 7) ^ (r & 7)) * 8;
    qsrc[j] = qbase + (long)r * ND + s;
    csrc[j] = cbase + (long)r * ND + s;
  }

  // read offsets: byte(row,kk,l4) = row*128 + ((kk<<6 | l4<<4) ^ ((row&7)<<4))
  //             = moff ^ (kk<<6), moff = row*128 + ((l4<<4) ^ ((row&7)<<4))
  int moff[8], noff[4];
  #pragma unroll
  for (int m = 0; m < 8; ++m) {
    const int row = wr * 128 + m * 16 + l15;
    moff[m] = row * 128 + ((l4 << 4) ^ ((row & 7) << 4));
  }
  #pragma unroll
  for (int n = 0; n < 4; ++n) {
    const int row = wc * 64 + n * 16 + l15;
    noff[n] = row * 128 + ((l4 << 4) ^ ((row & 7) << 4));
  }

#define STAGE8(BUF, T) do { \
    const long ko = (long)(T) * 64; \
    _Pragma("unroll") \
    for (int j = 0; j < 4; ++j) { \
      const int d = (j * 512 + tid) * 8; \
      gload_lds16(qsrc[j] + ko, &As[BUF][d]); \
      gload_lds16(csrc[j] + ko, &Bs[BUF][d]); \
    } \
  } while (0)

  STAGE8(0, 0);
  __syncthreads();                       // tile 0 landed

  #pragma unroll 2
  for (int t = 0; t < 8; ++t) {
    const int p = t & 1;
    if (t < 7) STAGE8(p ^ 1, t + 1);     // prefetch next tile, other buffer
    #pragma unroll
    for (int kk = 0; kk < 2; ++kk) {
      const int kx = kk << 6;
      bf16x8 a[8], b[4];
      #pragma unroll
      for (int m = 0; m < 8; ++m)
        a[m] = *(const bf16x8*)((const char*)As[p] + (moff[m] ^ kx));
      #pragma unroll
      for (int n = 0; n < 4; ++n)
        b[n] = *(const bf16x8*)((const char*)Bs[p] + (noff[n] ^ kx));
      __builtin_amdgcn_s_setprio(1);
      #pragma unroll
      for (int m = 0; m < 8; ++m)
        #pragma unroll
        for (int n = 0; n < 4; ++n)
          acc[m][n] = __builtin_amdgcn_mfma_f32_16x16x32_bf16(a[m], b[n], acc[m][n], 0, 0, 0);
      __builtin_amdgcn_s_setprio(0);
    }
    __syncthreads();   // drains this tile's reads + next tile's stage loads
  }
#undef STAGE8

  // ---- epilogue (acosh form) ----
  float* scr = (float*)&As[0][0];        // [256][4] floats, LDS reuse
  const int cb0 = bn * 256 + wc * 64 + l15;
  float ysv[4], bv[4];
  #pragma unroll
  for (int n = 0; n < 4; ++n) { ysv[n] = ysq[cb0 + n * 16]; bv[n] = b2[cb0 + n * 16]; }

  #pragma unroll
  for (int m = 0; m < 8; ++m) {
    #pragma unroll
    for (int r = 0; r < 4; ++r) {
      const int lrow = wr * 128 + m * 16 + l4 * 4 + r;
      const int grow = bm * 256 + lrow;
      const float4 rc = rcst[grow];
      const float negc = rc.x, Bc = rc.y, inv = rc.z, c2xs2 = rc.w;
      const float n4c = 4.f * negc;               // -4c
      float s = 0.f;
      #pragma unroll
      for (int n = 0; n < 4; ++n) {
        const float xy   = acc[m][n][r];
        const float By   = fmaf(negc, ysv[n], 1.f);
        const float P    = Bc * By;
        const float den2 = fmaf(c2xs2, ysv[n], fmaf(n4c, xy, 2.f));   // 2*den
        const float wv   = fmaf(den2, __builtin_amdgcn_rcpf(P), -1.f);
        const float t2   = fmaxf(fmaf(wv, wv, -1.f), 0.f);
        const float W    = wv + __builtin_amdgcn_sqrtf(t2);
        const float lg   = __builtin_amdgcn_logf(W);                  // log2
        s += __builtin_amdgcn_exp2f(fmaf(-inv, lg, bv[n]));
      }
      s += __shfl_xor(s, 1, 64);
      s += __shfl_xor(s, 2, 64);
      s += __shfl_xor(s, 4, 64);
      s += __shfl_xor(s, 8, 64);
      if (l15 == 0) scr[lrow * 4 + wc] = s;
    }
  }
  __syncthreads();
  if (tid < 256) {
    const float v = scr[tid * 4 + 0] + scr[tid * 4 + 1]
                  + scr[tid * 4 + 2] + scr[tid * 4 + 3];
    partials[(long)(bm * 256 + tid) * NCHUNK + bn] = v;
  }
}

// ---------- per-row LSE (no atomics) ----------
__global__ __launch_bounds__(64) void lse_row_kernel(
    const float* __restrict__ partials, const float* __restrict__ tgtl,
    float* __restrict__ rowloss)
{
  const int b = blockIdx.x;
  const int tid = threadIdx.x;
  float s = 0.f;
  for (int i = tid; i < NCHUNK; i += 64) s += partials[(long)b * NCHUNK + i];
  #pragma unroll
  for (int m = 1; m < 64; m <<= 1) s += __shfl_xor(s, m, 64);
  if (tid == 0) rowloss[b] = logf(s) - tgtl[b];
}

// ---------- deterministic final mean: one block, no atomics ----------
__global__ __launch_bounds__(256) void final_sum_kernel(
    const float* __restrict__ rowloss, float* __restrict__ out)
{
  const int tid = threadIdx.x;
  float s = rowloss[tid] + rowloss[tid + 256] + rowloss[tid + 512] + rowloss[tid + 768];
  #pragma unroll
  for (int m = 1; m < 64; m <<= 1) s += __shfl_xor(s, m, 64);
  __shared__ float red[4];
  if ((tid & 63) == 0) red[tid >> 6] = s;
  __syncthreads();
  if (tid == 0) out[0] = (red[0] + red[1] + red[2] + red[3]) * (1.0f / (float)NB);
}

// ---------- launch ----------
extern "C" void kernel_launch(void* const* d_in, const int* in_sizes, int n_in,
                              void* d_out, int out_size, void* d_ws, size_t ws_size,
                              hipStream_t stream) {
  const float* q    = (const float*)d_in[0];
  const float* cand = (const float*)d_in[1];
  const float* bias = (const float*)d_in[2];
  const float* curv = (const float*)d_in[3];
  const int*   tgt  = (const int*)d_in[4];
  float* out = (float*)d_out;

  char* ws = (char*)d_ws;
  unsigned short* cb = (unsigned short*)(ws);                 // 41,156,608
  unsigned short* qb = (unsigned short*)(ws + 41156608);      //  1,048,576
  float*  ysq        = (float*) (ws + 42205184);              //    160,768
  float*  b2         = (float*) (ws + 42365952);              //    160,768
  float4* rcst       = (float4*)(ws + 42526720);              //     16,384
  float*  tgtl       = (float*) (ws + 42543104);              //      4,096
  float*  rowloss    = (float*) (ws + 42547200);              //      4,096
  float*  partials   = (float*) (ws + 42551296);              //    643,072 -> end 43,194,368

  prep_all_kernel<<<NPAD / 4, 256, 0, stream>>>(q, cand, bias, curv, tgt,
                                                qb, cb, ysq, rcst, b2, tgtl);
  gemm_epi_kernel<<<628, 512, 0, stream>>>(qb, cb, rcst, ysq, b2, partials);
  lse_row_kernel<<<NB, 64, 0, stream>>>(partials, tgtl, rowloss);
  final_sum_kernel<<<1, 256, 0, stream>>>(rowloss, out);
}